// Round 1
// 563.991 us; speedup vs baseline: 1.0246x; 1.0246x over previous
//
#include <hip/hip_runtime.h>

typedef __attribute__((ext_vector_type(4))) float floatx4;
typedef __attribute__((ext_vector_type(8))) short bf16x8;

__device__ __forceinline__ unsigned short f2bf(float f) {
    union { float f; unsigned u; } v; v.f = f;
    unsigned r = v.u + 0x7fffu + ((v.u >> 16) & 1u);  // RNE
    return (unsigned short)(r >> 16);
}

// ---------------------------------------------------------------------------
// prep: pack weights into MFMA B-operand fragment blobs (bf16) + fuse biases.
// Wcat blob [kc=0..47][ntg=0..31][lane=0..63][j=0..7]:
//   element B[k][n], k = kc*32 + (lane>>4)*8 + j, n = ntg*16 + (lane&15)
//   k < 1024 -> W1[c][k][s] (c=n>>5, s=n&31), else W2[c][k-1024][s]
// W3 blob   [kc=0..15][ntg=0..31][lane][j]: B[k][n] = W3flat[k*512 + n]
// bias12[n] = b1flat[n] + b2flat[n];  bias3s[n] = sum_c b3[c*512+n]
// ---------------------------------------------------------------------------
__global__ void prep_kernel(const float* __restrict__ W1, const float* __restrict__ b1,
                            const float* __restrict__ W2, const float* __restrict__ b2,
                            const float* __restrict__ W3, const float* __restrict__ b3,
                            unsigned short* __restrict__ wcat, unsigned short* __restrict__ w3f,
                            float* __restrict__ bias12, float* __restrict__ bias3s)
{
    int tid = blockIdx.x * 256 + threadIdx.x;
    if (tid < 98304) {                       // 48 * 32 * 64 fragment-lanes
        int l  = tid & 63;
        int nt = (tid >> 6) & 31;
        int kc = tid >> 11;                  // 0..47
        int n  = nt * 16 + (l & 15);
        int k0 = kc * 32 + ((l >> 4) << 3);
        int c = n >> 5, s = n & 31;
        union { unsigned short us[8]; int4 v; } pk;
        const float* src = (k0 < 1024) ? (W1 + c * 32768 + k0 * 32 + s)
                                       : (W2 + c * 16384 + (k0 - 1024) * 32 + s);
        #pragma unroll
        for (int j = 0; j < 8; ++j) pk.us[j] = f2bf(src[j * 32]);
        *(int4*)(wcat + (size_t)tid * 8) = pk.v;
    } else if (tid < 131072) {               // 16 * 32 * 64 fragment-lanes for W3
        int t  = tid - 98304;
        int l  = t & 63;
        int nt = (t >> 6) & 31;
        int kc = t >> 11;                    // 0..15
        int n  = nt * 16 + (l & 15);
        int k0 = kc * 32 + ((l >> 4) << 3);
        union { unsigned short us[8]; int4 v; } pk;
        const float* src = W3 + k0 * 512 + n;
        #pragma unroll
        for (int j = 0; j < 8; ++j) pk.us[j] = f2bf(src[j * 512]);
        *(int4*)(w3f + (size_t)t * 8) = pk.v;
    } else if (tid < 131584) {
        int n = tid - 131072;
        bias12[n] = b1[n] + b2[n];
        float sacc = 0.f;
        #pragma unroll
        for (int c = 0; c < 16; ++c) sacc += b3[c * 512 + n];
        bias3s[n] = sacc;
    }
}

// ---------------------------------------------------------------------------
// fused main: per block 64 rows, 512 threads = 8 waves. Wave w owns cols
// [w*64, w*64+64). Same LDS as before (73728 B -> 2 blocks/CU) but 8 waves
// per block => 16 waves/CU = 4 waves/SIMD (occupancy 20% -> 40%).
// acc per wave shrinks 128 -> 64 regs; __launch_bounds__(512,4) caps VGPR
// at 128 so both blocks stay resident.
// A-prefetch deepened: issue chunk kb+2 while staging chunk kb+1 (register
// rotate), so HBM latency gets ~1.5 iterations of cover instead of <1.
// MFMA 16x16x32 bf16; A-frag: lane l holds A[m=l&15][k=(l>>4)*8+j];
// B-frag: B[k=(l>>4)*8+j][n=l&15]; C/D: col=l&15, row=(l>>4)*4+reg.
// ---------------------------------------------------------------------------
__global__ __launch_bounds__(512, 4) void fused_main(
    const float* __restrict__ app, const float* __restrict__ sp,
    const unsigned short* __restrict__ wcat, const unsigned short* __restrict__ w3f,
    const float* __restrict__ bias12, const float* __restrict__ bias3s,
    float* __restrict__ out)
{
    __shared__ unsigned short As[2][4][64][8];   // 8 KB  A-frag staging (dbuf)
    __shared__ unsigned short Hf[4][16][64][8];  // 64 KB H in A-frag layout

    const int tid = (int)threadIdx.x;
    const int w   = tid >> 6;                 // 0..7
    const int l   = tid & 63;
    const int rowbase = (int)blockIdx.x * 64;

    // cooperative A-staging mapping: thread -> (row sr, 4-wide k-chunk scc)
    const int sr  = tid >> 3;                 // 0..63
    const int scc = tid & 7;                  // 0..7  (k-chunk of 4)
    const float* appsrc = app + (size_t)(rowbase + sr) * 1024 + scc * 4;
    const float* spsrc  = sp  + (size_t)(rowbase + sr) * 512  + scc * 4;
    // frag position: m=sr -> mt=sr>>4, lane=(scc>>1)*16+(sr&15), j0=(scc&1)*4
    unsigned short* as0 = &As[0][sr >> 4][(scc >> 1) * 16 + (sr & 15)][(scc & 1) * 4];
    unsigned short* as1 = &As[1][sr >> 4][(scc >> 1) * 16 + (sr & 15)][(scc & 1) * 4];

    floatx4 acc[4][4];
    #pragma unroll
    for (int mt = 0; mt < 4; ++mt)
        #pragma unroll
        for (int nt = 0; nt < 4; ++nt)
            acc[mt][nt] = (floatx4){0.f, 0.f, 0.f, 0.f};

    // prologue: stage chunk 0 into buf 0, issue chunk 1 into registers
    {
        float4 p = *(const float4*)(appsrc);
        union { unsigned short us[4]; int2 v; } pk;
        pk.us[0] = f2bf(p.x); pk.us[1] = f2bf(p.y);
        pk.us[2] = f2bf(p.z); pk.us[3] = f2bf(p.w);
        *(int2*)as0 = pk.v;
    }
    float4 pA = *(const float4*)(appsrc + 32);   // chunk 1

    // ---- phase 1: H_pre = [app|sp] @ Wcat, K = 1536 (48 chunks of 32) ----
    for (int kb = 0; kb < 48; ++kb) {
        __syncthreads();
        const int buf = kb & 1;
        float4 pB;
        if (kb + 2 < 48) {                    // issue HBM load 2 chunks ahead
            const float* src = (kb + 2 < 32) ? (appsrc + (kb + 2) * 32)
                                             : (spsrc + (kb + 2 - 32) * 32);
            pB = *(const float4*)src;
        }
        bf16x8 bfrag[4];
        #pragma unroll
        for (int nt = 0; nt < 4; ++nt)
            bfrag[nt] = *(const bf16x8*)(wcat + (((size_t)kb * 32 + w * 4 + nt) * 64 + l) * 8);
        bf16x8 afrag[4];
        #pragma unroll
        for (int mt = 0; mt < 4; ++mt)
            afrag[mt] = *(const bf16x8*)(&As[buf][mt][l][0]);
        #pragma unroll
        for (int mt = 0; mt < 4; ++mt)
            #pragma unroll
            for (int nt = 0; nt < 4; ++nt)
                acc[mt][nt] = __builtin_amdgcn_mfma_f32_16x16x32_bf16(
                    afrag[mt], bfrag[nt], acc[mt][nt], 0, 0, 0);
        if (kb + 1 < 48) {                    // stage chunk kb+1 (loaded last iter)
            union { unsigned short us[4]; int2 v; } pk;
            pk.us[0] = f2bf(pA.x); pk.us[1] = f2bf(pA.y);
            pk.us[2] = f2bf(pA.z); pk.us[3] = f2bf(pA.w);
            *(int2*)((buf == 0) ? as1 : as0) = pk.v;
            pA = pB;
        }
    }

    // ---- phase 2: relu + bias, write Hf in A-frag layout ----
    #pragma unroll
    for (int nt = 0; nt < 4; ++nt) {
        const int colg = w * 64 + nt * 16 + (l & 15);
        const float bv = bias12[colg];
        const int kc  = colg >> 5;
        const int lhi = ((colg >> 3) & 3) << 4;
        const int j   = colg & 7;
        #pragma unroll
        for (int mt = 0; mt < 4; ++mt)
            #pragma unroll
            for (int r = 0; r < 4; ++r) {
                const int rlow = ((l >> 4) << 2) + r;      // rowg & 15
                float v = acc[mt][nt][r] + bv;
                v = fmaxf(v, 0.f);
                Hf[mt][kc][lhi + rlow][j] = f2bf(v);
            }
    }
    __syncthreads();

    // ---- phase 3: out = relu(Hf @ W3 + bias3s), K = 512 ----
    #pragma unroll
    for (int mt = 0; mt < 4; ++mt)
        #pragma unroll
        for (int nt = 0; nt < 4; ++nt)
            acc[mt][nt] = (floatx4){0.f, 0.f, 0.f, 0.f};

    for (int kc = 0; kc < 16; ++kc) {
        bf16x8 bfrag[4];
        #pragma unroll
        for (int nt = 0; nt < 4; ++nt)
            bfrag[nt] = *(const bf16x8*)(w3f + (((size_t)kc * 32 + w * 4 + nt) * 64 + l) * 8);
        bf16x8 afrag[4];
        #pragma unroll
        for (int mt = 0; mt < 4; ++mt)
            afrag[mt] = *(const bf16x8*)(&Hf[mt][kc][l][0]);
        #pragma unroll
        for (int mt = 0; mt < 4; ++mt)
            #pragma unroll
            for (int nt = 0; nt < 4; ++nt)
                acc[mt][nt] = __builtin_amdgcn_mfma_f32_16x16x32_bf16(
                    afrag[mt], bfrag[nt], acc[mt][nt], 0, 0, 0);
    }

    // ---- epilogue ----
    #pragma unroll
    for (int nt = 0; nt < 4; ++nt) {
        const int colg = w * 64 + nt * 16 + (l & 15);
        const float bv = bias3s[colg];
        #pragma unroll
        for (int mt = 0; mt < 4; ++mt)
            #pragma unroll
            for (int r = 0; r < 4; ++r) {
                const int rowg = mt * 16 + ((l >> 4) << 2) + r;
                float v = acc[mt][nt][r] + bv;
                v = fmaxf(v, 0.f);
                out[(size_t)(rowbase + rowg) * 512 + colg] = v;
            }
    }
}

extern "C" void kernel_launch(void* const* d_in, const int* in_sizes, int n_in,
                              void* d_out, int out_size, void* d_ws, size_t ws_size,
                              hipStream_t stream)
{
    const float* app = (const float*)d_in[0];
    const float* sp  = (const float*)d_in[1];
    const float* W1  = (const float*)d_in[2];
    const float* b1  = (const float*)d_in[3];
    const float* W2  = (const float*)d_in[4];
    const float* b2  = (const float*)d_in[5];
    const float* W3  = (const float*)d_in[6];
    const float* b3  = (const float*)d_in[7];

    char* ws = (char*)d_ws;
    unsigned short* wcat  = (unsigned short*)(ws);             // 1,572,864 B
    unsigned short* w3f   = (unsigned short*)(ws + 1572864);   //   524,288 B
    float*          b12   = (float*)(ws + 2097152);            //     2,048 B
    float*          b3s   = (float*)(ws + 2099200);            //     2,048 B

    prep_kernel<<<514, 256, 0, stream>>>(W1, b1, W2, b2, W3, b3, wcat, w3f, b12, b3s);

    float* outp = (float*)d_out;
    fused_main<<<65536 / 64, 512, 0, stream>>>(app, sp, wcat, w3f, b12, b3s, outp);
}